// Round 2
// baseline (418.783 us; speedup 1.0000x reference)
//
#include <hip/hip_runtime.h>

#define NTOK 49
#define CDIM 128
#define NH 4
#define NWIN 64

typedef unsigned short u16;
typedef unsigned int u32;
typedef __bf16 bf16x8 __attribute__((ext_vector_type(8)));
typedef float f32x4 __attribute__((ext_vector_type(4)));
typedef u16 u16x4 __attribute__((ext_vector_type(4)));

// RNE f32->bf16 via compiler cast (lowers to v_cvt_pk/cvt ops, ~1 VALU op).
__device__ __forceinline__ u16 f2bf(float f) {
  union { __bf16 h; u16 u; } c;
  c.h = (__bf16)f;
  return c.u;
}
__device__ __forceinline__ u32 pack2(float a, float b) {
  return (u32)f2bf(a) | ((u32)f2bf(b) << 16);
}
__device__ __forceinline__ bf16x8 ld8(const u16* p) { return *(const bf16x8*)p; }

// DPP add across the 16-lane row: xor1, xor2 (quad_perm), then ror4 + ror8.
#define DPP_ADD(v, ctrl)                                                            \
  v += __int_as_float(__builtin_amdgcn_update_dpp(0, __float_as_int(v), ctrl, 0xf, 0xf, true))

// ---------------- prep: transpose weights to bf16, build TRANSPOSED combined bias+mask ----
// ws layout (bytes): [0,98304) wqkvT bf16 (384x128)  [98304,131072) wprojT bf16 (128x128)
//                    [131072,131072+4MB) cmbT f32 [win][h][m(key) 64][n(query) 64], -1e30 pads
__global__ void prep_kernel(const float* __restrict__ qkv_w,
                            const float* __restrict__ proj_w,
                            const float* __restrict__ bias_table,
                            const float* __restrict__ mask,
                            const int* __restrict__ rel_index,
                            u16* __restrict__ wqkvT,
                            u16* __restrict__ wprojT,
                            float* __restrict__ cmbT) {
  int i = blockIdx.x * 256 + threadIdx.x;   // 1,048,576 threads
  if (i < 384 * 128) {
    int n = i >> 7, k = i & 127;
    wqkvT[i] = f2bf(qkv_w[k * 384 + n]);
  }
  if (i < 128 * 128) {
    int n = i >> 7, k = i & 127;
    wprojT[i] = f2bf(proj_w[k * 128 + n]);
  }
  int n = i & 63, m = (i >> 6) & 63, hh = (i >> 12) & 3, win = i >> 14;
  float v = -1e30f;
  if (n < NTOK && m < NTOK)
    v = bias_table[rel_index[n * NTOK + m] * NH + hh] + mask[(win * NTOK + n) * NTOK + m];
  cmbT[i] = v;   // cmbT[win][h][m][n], coalesced in n
}

// ---------------- fused window attention ----------------
// 512 threads = 8 waves. wave = head(0..3) x token-half hh(0..1).
// Each wave owns token tiles tmg = {2hh, 2hh+1} (rows tmg*16..+15) of its head.
// V is computed redundantly by both waves of a head (stays wave-private in regs).
//
// LDS map (u16 units, 26624 total = 52 KB -> 3 blocks/CU = 24 waves/CU):
//   XB [0,8192): x bf16 64x128, xor-swizzled 16B chunks (read-only after phase A)
//   R(h) = 8192 + h*4608 (region of head h):
//     Q : R(h)        + row*36 + d     (64x36, d=0..31)
//     K : R(h) + 2304 + row*36 + d
//     P : R(h)        + row*68 + m     (64x68) -- overlays Q/K (barrier #3 guards)
//     AO: R(h) + 2304 + row*36 + d     -- overlays P tail (barrier #4 guards)
#define RGN(h) (8192 + (h) * 4608)

__device__ __forceinline__ int xsw(int row, int col) {
  return (row << 7) + ((((col >> 3) ^ (row & 15)) << 3) | (col & 7));
}

__global__ __launch_bounds__(512, 6)
void swin_fused(const float* __restrict__ x, const float* __restrict__ qkv_b,
                const float* __restrict__ proj_b, const u16* __restrict__ wqkvT,
                const u16* __restrict__ wprojT, const float* __restrict__ cmbT,
                float* __restrict__ out) {
  __shared__ u16 lds[26624];
  const int tid  = threadIdx.x;
  const int wave = tid >> 6;
  const int head = wave & 3;
  const int hh   = wave >> 2;      // token-half
  const int lane = tid & 63;
  const int ln   = lane & 15;
  const int quad = lane >> 4;
  const int b    = blockIdx.x;
  const int win  = b & (NWIN - 1);
  const float scale = 0.17677669529663687f;  // 32^-0.5

  // ---- Phase A: x -> LDS bf16 (rows 49..63 zeroed), coalesced float4 loads ----
  {
    const float4* x4 = (const float4*)(x + (size_t)b * (NTOK * CDIM));
    for (int i = tid; i < (NTOK * CDIM) / 4; i += 512) {
      float4 f = x4[i];
      int e = i << 2;
      int row = e >> 7, col = e & 127;
      u16x4 v;
      v[0] = f2bf(f.x); v[1] = f2bf(f.y); v[2] = f2bf(f.z); v[3] = f2bf(f.w);
      *(u16x4*)&lds[xsw(row, col)] = v;
    }
    for (int i = tid; i < (15 * CDIM) / 4; i += 512) {
      int e = i << 2;
      int row = NTOK + (e >> 7), col = e & 127;
      u16x4 v = {0, 0, 0, 0};
      *(u16x4*)&lds[xsw(row, col)] = v;
    }
  }
  __syncthreads();   // #1

  // ---- Phase B: Q,K for own token-half -> LDS; V for ALL tokens -> registers ----
  u32 vbx[4][2], vby[4][2];   // packed bf16 V: tokens (4q+0,4q+1)/(4q+2,4q+3), [tok-tile][dim-tile]
  {
    // A-frags of x for own token half
    bf16x8 afh[2][4];
#pragma unroll
    for (int t = 0; t < 2; ++t)
#pragma unroll
      for (int ks = 0; ks < 4; ++ks)
        afh[t][ks] = ld8(&lds[xsw((2 * hh + t) * 16 + ln, ks * 32 + quad * 8)]);

    // Q (sect 0) and K (sect 1), own token half only
#pragma unroll
    for (int sect = 0; sect < 2; ++sect) {
#pragma unroll
      for (int tc = 0; tc < 2; ++tc) {
        int colg = sect * 128 + head * 32 + tc * 16 + ln;
        bf16x8 bw[4];
#pragma unroll
        for (int ks = 0; ks < 4; ++ks)
          bw[ks] = ld8(wqkvT + colg * 128 + ks * 32 + quad * 8);
        float cb = qkv_b[colg];
#pragma unroll
        for (int t = 0; t < 2; ++t) {
          f32x4 acc = {0.f, 0.f, 0.f, 0.f};
#pragma unroll
          for (int ks = 0; ks < 4; ++ks)
            acc = __builtin_amdgcn_mfma_f32_16x16x32_bf16(afh[t][ks], bw[ks], acc, 0, 0, 0);
          int row0 = (2 * hh + t) * 16 + quad * 4;   // C-layout: col=ln, row=quad*4+r
          if (sect == 0) {
#pragma unroll
            for (int r = 0; r < 4; ++r)
              lds[RGN(head) + (row0 + r) * 36 + tc * 16 + ln] = f2bf((acc[r] + cb) * scale);
          } else {
#pragma unroll
            for (int r = 0; r < 4; ++r)
              lds[RGN(head) + 2304 + (row0 + r) * 36 + tc * 16 + ln] = f2bf(acc[r] + cb);
          }
        }
      }
    }

    // V: all 4 token tiles (redundant across the two waves of this head; stays in regs)
#pragma unroll
    for (int tc = 0; tc < 2; ++tc) {
      int colg = 256 + head * 32 + tc * 16 + ln;
      bf16x8 bw[4];
#pragma unroll
      for (int ks = 0; ks < 4; ++ks)
        bw[ks] = ld8(wqkvT + colg * 128 + ks * 32 + quad * 8);
      float cb = qkv_b[colg];
#pragma unroll
      for (int tm = 0; tm < 4; ++tm) {
        bf16x8 afv[4];
#pragma unroll
        for (int ks = 0; ks < 4; ++ks)
          afv[ks] = ld8(&lds[xsw(tm * 16 + ln, ks * 32 + quad * 8)]);
        f32x4 acc = {0.f, 0.f, 0.f, 0.f};
#pragma unroll
        for (int ks = 0; ks < 4; ++ks)
          acc = __builtin_amdgcn_mfma_f32_16x16x32_bf16(afv[ks], bw[ks], acc, 0, 0, 0);
        vbx[tm][tc] = pack2(acc[0] + cb, acc[1] + cb);
        vby[tm][tc] = pack2(acc[2] + cb, acc[3] + cb);
      }
    }
  }
  __syncthreads();   // #2: Q/K of both halves visible

  // ---- Phase C: S = Q K^T (own rows x all keys), + bias+mask, exp, row-sum via DPP ----
  f32x4 s[2][4];
  {
    bf16x8 aq[2];
#pragma unroll
    for (int t = 0; t < 2; ++t)
      aq[t] = ld8(&lds[RGN(head) + ((2 * hh + t) * 16 + ln) * 36 + quad * 8]);
#pragma unroll
    for (int tn = 0; tn < 4; ++tn) {
      bf16x8 bk = ld8(&lds[RGN(head) + 2304 + (tn * 16 + ln) * 36 + quad * 8]);
#pragma unroll
      for (int t = 0; t < 2; ++t) {
        f32x4 z = {0.f, 0.f, 0.f, 0.f};
        s[t][tn] = __builtin_amdgcn_mfma_f32_16x16x32_bf16(aq[t], bk, z, 0, 0, 0);
      }
    }
  }
  {
    const float* cb = cmbT + ((size_t)((win << 2) | head) << 12);
#pragma unroll
    for (int t = 0; t < 2; ++t) {
#pragma unroll
      for (int tn = 0; tn < 4; ++tn) {
        f32x4 c4 = *(const f32x4*)&cb[(tn * 16 + ln) * 64 + (2 * hh + t) * 16 + quad * 4];
        s[t][tn] += c4;
      }
    }
  }
  // exp + row-sum in registers (before the barrier so the VALU work overlaps arrival spread)
  float inv[2][4];
  float ev[2][4][4];
#pragma unroll
  for (int t = 0; t < 2; ++t) {
#pragma unroll
    for (int r = 0; r < 4; ++r) {
      float e0 = __expf(s[t][0][r]);
      float e1 = __expf(s[t][1][r]);
      float e2 = __expf(s[t][2][r]);
      float e3 = __expf(s[t][3][r]);
      float tt = (e0 + e1) + (e2 + e3);
      DPP_ADD(tt, 0xB1);   // quad_perm [1,0,3,2] : xor 1
      DPP_ADD(tt, 0x4E);   // quad_perm [2,3,0,1] : xor 2
      DPP_ADD(tt, 0x124);  // row_ror:4
      DPP_ADD(tt, 0x128);  // row_ror:8
      inv[t][r] = 1.0f / tt;
      ev[t][0][r] = e0; ev[t][1][r] = e1; ev[t][2][r] = e2; ev[t][3][r] = e3;
    }
  }
  __syncthreads();   // #3: all Q/K reads done before P overlays Q/K
#pragma unroll
  for (int t = 0; t < 2; ++t) {
#pragma unroll
    for (int r = 0; r < 4; ++r) {
      int rr = (2 * hh + t) * 16 + quad * 4 + r;
      lds[RGN(head) + rr * 68 + 0 * 16 + ln] = f2bf(ev[t][0][r]);
      lds[RGN(head) + rr * 68 + 1 * 16 + ln] = f2bf(ev[t][1][r]);
      lds[RGN(head) + rr * 68 + 2 * 16 + ln] = f2bf(ev[t][2][r]);
      lds[RGN(head) + rr * 68 + 3 * 16 + ln] = f2bf(ev[t][3][r]);
    }
  }

  // ---- Phase D: O = P @ V (own rows); V B-frags via register shuffle ----
  {
    bf16x8 pa[2][2];
#pragma unroll
    for (int t = 0; t < 2; ++t)
#pragma unroll
      for (int ks = 0; ks < 2; ++ks)
        pa[t][ks] = ld8(&lds[RGN(head) + ((2 * hh + t) * 16 + ln) * 68 + ks * 32 + quad * 8]);
    __syncthreads();   // #4: all P reads done before AO overlays P
    f32x4 o[2][2];
#pragma unroll
    for (int t = 0; t < 2; ++t)
#pragma unroll
      for (int tc = 0; tc < 2; ++tc) { f32x4 z = {0.f,0.f,0.f,0.f}; o[t][tc] = z; }
#pragma unroll
    for (int ks = 0; ks < 2; ++ks) {
#pragma unroll
      for (int tc = 0; tc < 2; ++tc) {
        union { u32 u[4]; bf16x8 v; } bv;
#pragma unroll
        for (int p = 0; p < 4; ++p) {
          int src = ((2 * (quad & 1) + (p >> 1)) << 4) | ln;
          int a0 = __shfl((int)((p & 1) ? vby[2 * ks][tc]     : vbx[2 * ks][tc]),     src);
          int a1 = __shfl((int)((p & 1) ? vby[2 * ks + 1][tc] : vbx[2 * ks + 1][tc]), src);
          bv.u[p] = (u32)((quad < 2) ? a0 : a1);
        }
#pragma unroll
        for (int t = 0; t < 2; ++t)
          o[t][tc] = __builtin_amdgcn_mfma_f32_16x16x32_bf16(pa[t][ks], bv.v, o[t][tc], 0, 0, 0);
      }
    }
#pragma unroll
    for (int t = 0; t < 2; ++t) {
      int row0 = (2 * hh + t) * 16 + quad * 4;
#pragma unroll
      for (int tc = 0; tc < 2; ++tc)
#pragma unroll
        for (int r = 0; r < 4; ++r)
          lds[RGN(head) + 2304 + (row0 + r) * 36 + tc * 16 + ln] = f2bf(o[t][tc][r] * inv[t][r]);
    }
  }
  __syncthreads();   // #5: AO of all heads visible

  // ---- Phase E: out = AO @ proj_w + proj_b (own token rows, own head's 32 cols) ----
  {
    bf16x8 aof[2][4];
#pragma unroll
    for (int t = 0; t < 2; ++t)
#pragma unroll
      for (int ks = 0; ks < 4; ++ks)
        aof[t][ks] = ld8(&lds[RGN(ks) + 2304 + ((2 * hh + t) * 16 + ln) * 36 + quad * 8]);
#pragma unroll
    for (int tj = 0; tj < 2; ++tj) {
      int colg = head * 32 + tj * 16 + ln;
      bf16x8 bw[4];
#pragma unroll
      for (int ks = 0; ks < 4; ++ks)
        bw[ks] = ld8(wprojT + colg * 128 + ks * 32 + quad * 8);
      float pb = proj_b[colg];
#pragma unroll
      for (int t = 0; t < 2; ++t) {
        f32x4 acc = {0.f, 0.f, 0.f, 0.f};
#pragma unroll
        for (int ks = 0; ks < 4; ++ks)
          acc = __builtin_amdgcn_mfma_f32_16x16x32_bf16(aof[t][ks], bw[ks], acc, 0, 0, 0);
        int row0 = (2 * hh + t) * 16 + quad * 4;
#pragma unroll
        for (int r = 0; r < 4; ++r) {
          int rr = row0 + r;
          if (rr < NTOK)
            out[((size_t)b * NTOK + rr) * CDIM + colg] = acc[r] + pb;
        }
      }
    }
  }
}

extern "C" void kernel_launch(void* const* d_in, const int* in_sizes, int n_in,
                              void* d_out, int out_size, void* d_ws, size_t ws_size,
                              hipStream_t stream) {
  const float* x          = (const float*)d_in[0];
  const float* qkv_w      = (const float*)d_in[1];
  const float* qkv_b      = (const float*)d_in[2];
  const float* proj_w     = (const float*)d_in[3];
  const float* proj_b     = (const float*)d_in[4];
  const float* bias_table = (const float*)d_in[5];
  const float* mask       = (const float*)d_in[6];
  const int*   rel_index  = (const int*)d_in[7];

  u16*   wqkvT  = (u16*)d_ws;
  u16*   wprojT = wqkvT + 384 * 128;
  float* cmbT   = (float*)((char*)d_ws + 131072);

  const int Bt = in_sizes[0] / (NTOK * CDIM);   // 4096

  prep_kernel<<<4096, 256, 0, stream>>>(qkv_w, proj_w, bias_table, mask, rel_index,
                                        wqkvT, wprojT, cmbT);
  swin_fused<<<Bt, 512, 0, stream>>>(x, qkv_b, proj_b, wqkvT, wprojT, cmbT, (float*)d_out);
}